// Round 10
// baseline (2376.913 us; speedup 1.0000x reference)
//
#include <hip/hip_runtime.h>
#include <cstdint>
#include <cstddef>

typedef _Float16 f16x2 __attribute__((ext_vector_type(2)));
typedef _Float16 half4 __attribute__((ext_vector_type(4)));
typedef _Float16 half8 __attribute__((ext_vector_type(8)));
typedef float f32x4 __attribute__((ext_vector_type(4)));

static constexpr int BB = 64;    // batch
static constexpr int TT = 1024;  // time steps
static constexpr int FF = 512;   // input features
static constexpr int UU = 256;   // hidden units per direction
static constexpr int NZ = 1024;  // 4*UU gate width

// U on-CU split (per thread, 32 uint4 total): 20 reg + 8 LDS + 4 L2-stream
static constexpr int UREG = 20;
static constexpr int ULDS = 8;
static constexpr size_t ULDS_BYTES = (size_t)ULDS * 1024 * 16;   // 128 KiB
static constexpr size_t H_SECT = 144;                            // 128 data + 16 pad
static constexpr size_t LSTM_SHBYTES = ULDS_BYTES + 1024;        // ~129 KiB -> 1 block/CU

__device__ __forceinline__ f16x2 bc16(unsigned int v) { return __builtin_bit_cast(f16x2, v); }

// Raw barrier: drains LDS ops only; vmcnt (global loads) survives.
__device__ __forceinline__ void bar_lgkm()
{
    asm volatile("s_waitcnt lgkmcnt(0)\n\ts_barrier" ::: "memory");
}

// quad (4-lane) sum via DPP quad_perm: [1,0,3,2]=0xB1 then [2,3,0,1]=0x4E
__device__ __forceinline__ float qsum(float v)
{
    int b1 = __builtin_amdgcn_mov_dpp(__builtin_bit_cast(int, v), 0xB1, 0xf, 0xf, true);
    v += __builtin_bit_cast(float, b1);
    int b2 = __builtin_amdgcn_mov_dpp(__builtin_bit_cast(int, v), 0x4E, 0xf, 0xf, true);
    v += __builtin_bit_cast(float, b2);
    return v;
}

// ---------------------------------------------------------------------------
// Cast x fp32 -> f16 (flat)
// ---------------------------------------------------------------------------
__global__ __launch_bounds__(256) void enc_cast_x(
    const float* __restrict__ x, _Float16* __restrict__ x16, int n4)
{
    int stride = gridDim.x * 256;
    for (int i = blockIdx.x * 256 + threadIdx.x; i < n4; i += stride) {
        float4 v = ((const float4*)x)[i];
        half4 o;
        o.x = (_Float16)v.x; o.y = (_Float16)v.y;
        o.z = (_Float16)v.z; o.w = (_Float16)v.w;
        ((half4*)x16)[i] = o;
    }
}

// ---------------------------------------------------------------------------
// W [512,1024] fp32 -> WT [dir][1024][512] f16 (transposed)
// ---------------------------------------------------------------------------
__global__ __launch_bounds__(256) void enc_cast_wt(
    const float* __restrict__ Wf, const float* __restrict__ Wb,
    _Float16* __restrict__ WT)
{
    __shared__ float tile[64][65];
    const int t = threadIdx.x;
    const int k0 = blockIdx.x * 64;
    const int n0 = blockIdx.y * 64;
    const int d = blockIdx.z;
    const float* W = d ? Wb : Wf;
    _Float16* WTd = WT + (size_t)d * NZ * FF;
#pragma unroll
    for (int p = 0; p < 16; ++p) {
        int idx = p * 256 + t;
        int r = idx >> 6, c = idx & 63;
        tile[r][c] = W[(size_t)(k0 + r) * NZ + n0 + c];
    }
    __syncthreads();
#pragma unroll
    for (int p = 0; p < 16; ++p) {
        int idx = p * 256 + t;
        int r = idx >> 6, c = idx & 63;
        WTd[(size_t)(n0 + r) * FF + k0 + c] = (_Float16)tile[c][r];
    }
}

// ---------------------------------------------------------------------------
// Pack U: Upkr2[(d*128 + k2)*256 + j] = uint4 of 4 gate words;
// word g = { U_d[2*k2][g*256+j], U_d[2*k2+1][g*256+j] } as f16x2.
// ---------------------------------------------------------------------------
__global__ __launch_bounds__(256) void enc_pack_u16v2(
    const float* __restrict__ Uf, const float* __restrict__ Ub,
    uint4* __restrict__ Upkr2)
{
    int idx = blockIdx.x * 256 + threadIdx.x;     // 0 .. 65535
    if (idx >= 2 * 128 * 256) return;
    int d  = idx >> 15;
    int k2 = (idx >> 8) & 127;
    int j  = idx & 255;
    int k = 2 * k2;
    const float* Ud = d ? Ub : Uf;
    unsigned int w[4];
#pragma unroll
    for (int g = 0; g < 4; ++g) {
        f16x2 h;
        h.x = (_Float16)Ud[(size_t)k * NZ + g * 256 + j];
        h.y = (_Float16)Ud[(size_t)(k + 1) * NZ + g * 256 + j];
        w[g] = __builtin_bit_cast(unsigned int, h);
    }
    Upkr2[idx] = make_uint4(w[0], w[1], w[2], w[3]);
}

__global__ __launch_bounds__(256) void enc_zero(float* __restrict__ p, int n)
{
    int i = blockIdx.x * 256 + threadIdx.x;
    if (i < n) p[i] = 0.f;
}

// ---------------------------------------------------------------------------
// MFMA GEMM: xz16[r, n] = x16_row(r) . W_d[:, n] + b_d[n]   (unchanged)
// ---------------------------------------------------------------------------
__global__ __launch_bounds__(256) void enc_gemm16(
    const _Float16* __restrict__ x16, const _Float16* __restrict__ WT,
    const float* __restrict__ bf, const float* __restrict__ bb,
    _Float16* __restrict__ xz16, int c0, int CT)
{
    __shared__ __align__(16) _Float16 Ash[128][40];
    __shared__ __align__(16) _Float16 Bsh[128][40];

    const int t = threadIdx.x;
    const int r0 = blockIdx.x * 128;
    const int n0 = blockIdx.y * 128;
    const int MperD = BB * CT;
    const int d = r0 / MperD;

    const int srow = t >> 2;
    const int koff = (t & 3) * 8;

    auto xrowptr = [&](int r) -> const _Float16* {
        int rd = r - d * MperD;
        int b = rd / CT;
        int tl = rd - b * CT;
        int tsrc = d ? (TT - 1 - (c0 + tl)) : (c0 + tl);
        return x16 + ((size_t)b * TT + tsrc) * FF;
    };
    const _Float16* ap0 = xrowptr(r0 + srow);
    const _Float16* ap1 = xrowptr(r0 + 64 + srow);
    const _Float16* wp0 = WT + (size_t)(d * NZ + n0 + srow) * FF;
    const _Float16* wp1 = wp0 + (size_t)64 * FF;

    const int lane = t & 63;
    const int w = t >> 6;
    const int wm = w >> 1, wn = w & 1;
    const int l15 = lane & 15;
    const int kq = (lane >> 4) * 8;

    f32x4 acc[4][4];
#pragma unroll
    for (int i = 0; i < 4; ++i)
#pragma unroll
        for (int j = 0; j < 4; ++j) acc[i][j] = (f32x4)0.f;

    for (int ks = 0; ks < FF / 32; ++ks) {
        const int k0 = ks * 32;
        uint4 av0 = *(const uint4*)(ap0 + k0 + koff);
        uint4 av1 = *(const uint4*)(ap1 + k0 + koff);
        uint4 bv0 = *(const uint4*)(wp0 + k0 + koff);
        uint4 bv1 = *(const uint4*)(wp1 + k0 + koff);
        __syncthreads();
        *(uint4*)&Ash[srow][koff]      = av0;
        *(uint4*)&Ash[64 + srow][koff] = av1;
        *(uint4*)&Bsh[srow][koff]      = bv0;
        *(uint4*)&Bsh[64 + srow][koff] = bv1;
        __syncthreads();

        half8 af[4], bfr[4];
#pragma unroll
        for (int mf = 0; mf < 4; ++mf)
            af[mf] = *(const half8*)&Ash[wm * 64 + mf * 16 + l15][kq];
#pragma unroll
        for (int nf = 0; nf < 4; ++nf)
            bfr[nf] = *(const half8*)&Bsh[wn * 64 + nf * 16 + l15][kq];
#pragma unroll
        for (int mf = 0; mf < 4; ++mf)
#pragma unroll
            for (int nf = 0; nf < 4; ++nf)
                acc[mf][nf] = __builtin_amdgcn_mfma_f32_16x16x32_f16(
                    af[mf], bfr[nf], acc[mf][nf], 0, 0, 0);
    }

    const float* bd = d ? bb : bf;
    const int rbase = r0 + wm * 64;
    const int cbase = n0 + wn * 64;
#pragma unroll
    for (int nf = 0; nf < 4; ++nf) {
        const int cc = cbase + nf * 16 + l15;
        const float bia = bd[cc];
#pragma unroll
        for (int mf = 0; mf < 4; ++mf) {
#pragma unroll
            for (int rg = 0; rg < 4; ++rg) {
                int rr = rbase + mf * 16 + (lane >> 4) * 4 + rg;
                xz16[(size_t)rr * NZ + cc] = (_Float16)(acc[mf][nf][rg] + bia);
            }
        }
    }
}

// ---------------------------------------------------------------------------
// Single-CU full-chain recurrence: 128 blocks = chains, 1024 threads.
// t = j*4 + q: lane q owns k-quarter q (k2 in [q*32,(q+1)*32)) x 4 gates of
// unit j. U 3-tier: ureg[20] + ulds[8 rows][1024] + 4 uint4 L2-streamed/step
// (loop-invariant addresses -> L2-resident; compiler may hoist to regs).
// h[256] f16 in LDS: 4 sections of 144 B (128 data + 16 pad) -> the 4 quad
// broadcast streams hit distinct banks. Quad-DPP reduce gives every lane the
// full z; gates duplicated x4 (deterministic); q==0 lanes write h/out/state.
// 2 raw lgkm barriers per step; no cross-CU exchange, no spin.
// ---------------------------------------------------------------------------
__device__ __forceinline__ float sigm_f(float xv)
{
    return 1.0f / (1.0f + __expf(-xv));
}
__device__ __forceinline__ float tanh_f(float xv)
{
    return 2.0f / (1.0f + __expf(-2.0f * xv)) - 1.0f;
}

__global__ __launch_bounds__(1024) void enc_lstm_full(
    const _Float16* __restrict__ xz16, const uint4* __restrict__ Upkr2,
    float* __restrict__ hstate, float* __restrict__ cstate,
    float* __restrict__ out, int c0, int CT)
{
    extern __shared__ char smem2[];
    uint4* ulds = (uint4*)smem2;                     // [8][1024] uint4
    char*  hbase = smem2 + ULDS_BYTES;               // 4 sections x 144 B

    const int t = threadIdx.x;
    const int q = t & 3;
    const int j = t >> 2;          // 0..255
    const int c = blockIdx.x;      // chain 0..127
    const int d = c >> 6;
    const int b = c & 63;
    const int jq4 = t;             // = j*4 + q, LDS-U index

    // ---- persistent U ----
    const uint4* Uq = Upkr2 + ((size_t)d * 128 + q * 32) * 256 + j;
    uint4 ureg[UREG];
#pragma unroll
    for (int m = 0; m < UREG; ++m) ureg[m] = Uq[(size_t)m * 256];
#pragma unroll
    for (int m = 0; m < ULDS; ++m)
        ulds[(size_t)m * 1024 + jq4] = Uq[(size_t)(UREG + m) * 256];
    const uint4* Ul2 = Uq + (size_t)(UREG + ULDS) * 256;   // 4 words: [0,256,512,768]

    // ---- state init ----
    float cr = cstate[(size_t)c * UU + j];           // duplicated across quad
    float hn = 0.f;
    if (t < 256) {
        _Float16 hv = (_Float16)hstate[(size_t)c * UU + t];
        *(unsigned short*)(hbase + (t >> 6) * H_SECT + (t & 63) * 2) =
            __builtin_bit_cast(unsigned short, hv);
    }
    __syncthreads();

    const _Float16* xzrow = xz16 + (size_t)c * CT * NZ;
    float* outb = out + (size_t)b * TT * (2 * UU) + d * UU;
    const char* hrd = hbase + q * H_SECT;            // this lane's h quarter

    // first step's xz (gate q of unit j)
    unsigned short xq = *((const unsigned short*)xzrow + q * 256 + j);

    for (int tl = 0; tl < CT; ++tl) {
        // L2-tier U loads (fixed addresses -> L2 hit; consumed at dot end)
        uint4 u28 = Ul2[0];
        uint4 u29 = Ul2[256];
        uint4 u30 = Ul2[512];
        uint4 u31 = Ul2[768];

        float a0 = 0.f, a1 = 0.f, a2 = 0.f, a3 = 0.f;
        auto dotw = [&](const uint4& uv, unsigned int hw) {
            f16x2 h2 = bc16(hw);
            a0 = __builtin_amdgcn_fdot2(h2, bc16(uv.x), a0, false);
            a1 = __builtin_amdgcn_fdot2(h2, bc16(uv.y), a1, false);
            a2 = __builtin_amdgcn_fdot2(h2, bc16(uv.z), a2, false);
            a3 = __builtin_amdgcn_fdot2(h2, bc16(uv.w), a3, false);
        };

        // reg tier: h uint4 r covers k2 4r..4r+3 -> U words 4r..4r+3
#pragma unroll
        for (int r = 0; r < 5; ++r) {
            uint4 hq = *(const uint4*)(hrd + r * 16);
            dotw(ureg[4 * r + 0], hq.x);
            dotw(ureg[4 * r + 1], hq.y);
            dotw(ureg[4 * r + 2], hq.z);
            dotw(ureg[4 * r + 3], hq.w);
        }
        // LDS tier: U words 20..27 (read just-in-time, low pressure)
#pragma unroll
        for (int r = 5; r < 7; ++r) {
            uint4 hq = *(const uint4*)(hrd + r * 16);
#pragma unroll
            for (int e = 0; e < 4; ++e) {
                uint4 uv = ulds[(size_t)(4 * (r - 5) + e) * 1024 + jq4];
                dotw(uv, (&hq.x)[e]);
            }
        }
        // L2 tier: U words 28..31
        {
            uint4 hq = *(const uint4*)(hrd + 7 * 16);
            dotw(u28, hq.x);
            dotw(u29, hq.y);
            dotw(u30, hq.z);
            dotw(u31, hq.w);
        }

        // inject xz on lane q into accumulator q (summed once by quad reduce)
        {
            float xv = (float)__builtin_bit_cast(_Float16, xq);
            a0 += (q == 0) ? xv : 0.f;
            a1 += (q == 1) ? xv : 0.f;
            a2 += (q == 2) ? xv : 0.f;
            a3 += (q == 3) ? xv : 0.f;
        }
        float zi = qsum(a0), zf = qsum(a1), zg = qsum(a2), zo = qsum(a3);

        // gates (duplicated across quad — deterministic identical results)
        float ig = sigm_f(zi), fg = sigm_f(zf), gg = tanh_f(zg), og = sigm_f(zo);
        cr = fg * cr + ig * gg;
        hn = og * tanh_f(cr);
        unsigned short hbits =
            __builtin_bit_cast(unsigned short, (_Float16)hn);

        // prefetch next step's xz (vmcnt survives raw barriers)
        {
            int tn = (tl + 1 < CT) ? tl + 1 : tl;
            xq = *((const unsigned short*)(xzrow + (size_t)tn * NZ) + q * 256 + j);
        }

        bar_lgkm();                          // bar1: all h reads complete
        if (q == 0) {
            *(unsigned short*)(hbase + (j >> 6) * H_SECT + (j & 63) * 2) = hbits;
            int tsrc = d ? (TT - 1 - (c0 + tl)) : (c0 + tl);
            outb[(size_t)tsrc * (2 * UU) + j] = hn;
        }
        bar_lgkm();                          // bar2: new h visible
    }

    if (q == 0) {
        hstate[(size_t)c * UU + j] = hn;
        cstate[(size_t)c * UU + j] = cr;
    }
}

// ---------------------------------------------------------------------------
// Final h/c copy into d_out tail sections
// ---------------------------------------------------------------------------
__global__ __launch_bounds__(256) void enc_final(
    const float* __restrict__ hstate, const float* __restrict__ cstate,
    float* __restrict__ out)
{
    int idx = blockIdx.x * 256 + threadIdx.x;
    if (idx >= 2 * BB * UU) return;
    int d = idx / (BB * UU);
    int rem = idx - d * (BB * UU);
    int b = rem / UU;
    int j = rem - b * UU;
    size_t OUT_H = (size_t)BB * TT * (2 * UU);
    size_t HSZ = (size_t)BB * (2 * UU);
    out[OUT_H + (size_t)b * (2 * UU) + d * UU + j] = hstate[idx];
    out[OUT_H + HSZ + (size_t)b * (2 * UU) + d * UU + j] = cstate[idx];
}

// ---------------------------------------------------------------------------
extern "C" void kernel_launch(void* const* d_in, const int* in_sizes, int n_in,
                              void* d_out, int out_size, void* d_ws, size_t ws_size,
                              hipStream_t stream)
{
    const float* x  = (const float*)d_in[0];
    const float* Wf = (const float*)d_in[1];
    const float* Uf = (const float*)d_in[2];
    const float* bf = (const float*)d_in[3];
    const float* Wb = (const float*)d_in[4];
    const float* Ub = (const float*)d_in[5];
    const float* bb = (const float*)d_in[6];
    float* out = (float*)d_out;

    const size_t x16_bytes   = (size_t)BB * TT * FF * 2;             // 64 MiB
    const size_t wt_bytes    = (size_t)2 * NZ * FF * 2;              // 2 MiB
    const size_t upk_bytes   = (size_t)2 * 128 * 256 * sizeof(uint4);// 1 MiB
    const size_t state_bytes = (size_t)2 * BB * UU * sizeof(float);  // 128 KiB each
    const size_t fixed = x16_bytes + wt_bytes + upk_bytes + 2 * state_bytes;

    int CT = TT;
    while (CT > 8) {
        size_t need = fixed + (size_t)2 * BB * CT * NZ * 2;
        if (need <= ws_size) break;
        CT >>= 1;
    }

    char* wsb = (char*)d_ws;
    _Float16* x16 = (_Float16*)wsb;
    _Float16* WT  = (_Float16*)(wsb + x16_bytes);
    uint4* Upkr2  = (uint4*)(wsb + x16_bytes + wt_bytes);
    float* hstate = (float*)(wsb + x16_bytes + wt_bytes + upk_bytes);
    float* cstate = hstate + 2 * BB * UU;
    _Float16* xz16 = (_Float16*)(wsb + fixed);

    (void)hipFuncSetAttribute(reinterpret_cast<const void*>(enc_lstm_full),
                              hipFuncAttributeMaxDynamicSharedMemorySize,
                              (int)LSTM_SHBYTES);

    enc_cast_x<<<4096, 256, 0, stream>>>(x, x16, BB * TT * FF / 4);
    enc_cast_wt<<<dim3(8, 16, 2), 256, 0, stream>>>(Wf, Wb, WT);
    enc_pack_u16v2<<<(2 * 128 * 256 + 255) / 256, 256, 0, stream>>>(Uf, Ub, Upkr2);
    enc_zero<<<(2 * 2 * BB * UU + 255) / 256, 256, 0, stream>>>(hstate, 2 * 2 * BB * UU);

    for (int c0 = 0; c0 < TT; c0 += CT) {
        dim3 ggrid((2 * BB * CT) / 128, NZ / 128);
        enc_gemm16<<<ggrid, 256, 0, stream>>>(x16, WT, bf, bb, xz16, c0, CT);
        enc_lstm_full<<<128, 1024, LSTM_SHBYTES, stream>>>(
            xz16, Upkr2, hstate, cstate, out, c0, CT);
    }
    enc_final<<<(2 * BB * UU + 255) / 256, 256, 0, stream>>>(hstate, cstate, out);
}